// Round 4
// baseline (323.183 us; speedup 1.0000x reference)
//
#include <hip/hip_runtime.h>

#define D_IN 128
#define D_H 256
#define D_OUT 128
#define N_SETS 8192

typedef short short8 __attribute__((ext_vector_type(8)));
typedef short short4v __attribute__((ext_vector_type(4)));
typedef float floatx4 __attribute__((ext_vector_type(4)));

__device__ inline unsigned short f32_bf16(float f) {
    unsigned int u = __float_as_uint(f);
    u += 0x7FFFu + ((u >> 16) & 1u);   // round-to-nearest-even
    return (unsigned short)(u >> 16);
}

// blocks [0,32): swizzle W1/W2 into bf16 MFMA fragment order.
// frag f -> 64 lanes x 8 bf16, lane l holds M[k = c*32 + (l>>4)*8 + j][n = nt*16 + (l&15)].
// (Same bytes serve as B-frag of M and as A-frag of M^T.)
// blocks [32,1064): zero out (8192x128) and counts (8192).
__global__ void setup_kernel(const float* __restrict__ W1, const float* __restrict__ W2,
                             unsigned short* __restrict__ W1s, unsigned short* __restrict__ W2s,
                             float4* __restrict__ out4, float4* __restrict__ cnt4) {
    if (blockIdx.x < 32) {
        int t = blockIdx.x * 256 + threadIdx.x;
        int l = t & 63;
        int f = (t >> 6) & 63;
        int q = l >> 4, r = l & 15;
        if (t < 4096) {                      // W1: 16 n-tiles x 4 k-chunks
            int nt = f >> 2, c = f & 3;
            int k0 = c * 32 + q * 8, n = nt * 16 + r;
            unsigned short v[8];
#pragma unroll
            for (int j = 0; j < 8; j++) v[j] = f32_bf16(W1[(k0 + j) * D_H + n]);
#pragma unroll
            for (int j = 0; j < 8; j++) W1s[f * 512 + l * 8 + j] = v[j];
        } else {                             // W2: 8 n-tiles x 8 k-chunks
            int nt = f >> 3, c = f & 7;
            int k0 = c * 32 + q * 8, n = nt * 16 + r;
            unsigned short v[8];
#pragma unroll
            for (int j = 0; j < 8; j++) v[j] = f32_bf16(W2[(k0 + j) * D_OUT + n]);
#pragma unroll
            for (int j = 0; j < 8; j++) W2s[f * 512 + l * 8 + j] = v[j];
        }
    } else {
        int i = (blockIdx.x - 32) * 256 + threadIdx.x;
        float4 z = make_float4(0.f, 0.f, 0.f, 0.f);
        if (i < 262144) out4[i] = z;               // out: 8192*128 floats
        else if (i < 264192) cnt4[i - 262144] = z; // counts: 8192 floats
    }
}

// Block = 64 tokens, 4 waves, n-split: wave w computes h1-col tiles {4w..4w+3}
// (layer 1 done transposed: A=W1-frag, B=x-frag, so C/D packs as b64 h1 writes)
// and out-col tiles {2w,2w+1} (layer 2). acc2 = 32 regs.
// LDS: xA [64][136]bf16 (17408 B) | h1A [64][266]bf16 (34048 B);
// h2T [128][68]f32 (34816 B) overlays from offset 0 AFTER the phase-2 barrier
// (xA dead after xf loads, h1A dead after phase 2). sseg separate.
__global__ __launch_bounds__(256, 3) void ds_main(
    const float* __restrict__ x, const int* __restrict__ seg,
    const unsigned short* __restrict__ W1s, const float* __restrict__ b1,
    const unsigned short* __restrict__ W2s, const float* __restrict__ b2,
    float* __restrict__ out, float* __restrict__ counts)
{
    __shared__ unsigned char smraw[51456];
    unsigned short* xA  = (unsigned short*)smraw;             // [64][136] bf16 (uses 128 cols)
    unsigned short* h1A = (unsigned short*)(smraw + 17408);   // [64][266] bf16 (uses 256 cols)
    float* h2T = (float*)smraw;                               // [128][68] fp32 overlay
    __shared__ int sseg[64];

    const int tid = threadIdx.x;
    const int wave = tid >> 6, lane = tid & 63;
    const int r = lane & 15, q = lane >> 4;
    const int base = blockIdx.x * 64;

    if (tid < 64) sseg[tid] = seg[base + tid];

    // ---- phase 0: stage x tile -> LDS bf16 (coalesced float4 global reads) ----
    {
        const int row = tid >> 2, p = tid & 3;
        const float* xp = x + (size_t)(base + row) * D_IN + p * 32;
        unsigned short* dst = xA + row * 136 + p * 32;
#pragma unroll
        for (int u = 0; u < 4; u++) {
            float4 v0 = *(const float4*)(xp + u * 8);
            float4 v1 = *(const float4*)(xp + u * 8 + 4);
            short8 w;
            w[0] = (short)f32_bf16(v0.x); w[1] = (short)f32_bf16(v0.y);
            w[2] = (short)f32_bf16(v0.z); w[3] = (short)f32_bf16(v0.w);
            w[4] = (short)f32_bf16(v1.x); w[5] = (short)f32_bf16(v1.y);
            w[6] = (short)f32_bf16(v1.z); w[7] = (short)f32_bf16(v1.w);
            *(short8*)(dst + u * 8) = w;
        }
    }
    __syncthreads();

    // ---- x fragments (MFMA B operand of x^T): xf[tt][c][lane (q,r)] = x[tt*16+r][c*32+q*8..+7] ----
    short8 xf[4][4];
#pragma unroll
    for (int tt = 0; tt < 4; tt++)
#pragma unroll
        for (int c = 0; c < 4; c++)
            xf[tt][c] = *(const short8*)(xA + (tt * 16 + r) * 136 + c * 32 + q * 8);

    // ---- phase 1 (transposed): D[h1col = nt*16 + q*4+i][tok = tt*16 + r] ----
#pragma unroll
    for (int nti = 0; nti < 4; nti++) {
        const int nt = wave * 4 + nti;
        short8 wf[4];
#pragma unroll
        for (int c = 0; c < 4; c++)
            wf[c] = *(const short8*)(W1s + (nt * 4 + c) * 512 + lane * 8);
        floatx4 acc[4];
#pragma unroll
        for (int tt = 0; tt < 4; tt++) acc[tt] = (floatx4){0.f, 0.f, 0.f, 0.f};
#pragma unroll
        for (int c = 0; c < 4; c++)
#pragma unroll
            for (int tt = 0; tt < 4; tt++)
                acc[tt] = __builtin_amdgcn_mfma_f32_16x16x32_bf16(wf[c], xf[tt][c], acc[tt], 0, 0, 0);
        floatx4 bv = *(const floatx4*)(b1 + nt * 16 + q * 4);
#pragma unroll
        for (int tt = 0; tt < 4; tt++) {
            short4v pk;
#pragma unroll
            for (int i = 0; i < 4; i++)
                pk[i] = (short)f32_bf16(fmaxf(acc[tt][i] + bv[i], 0.f));
            *(short4v*)(h1A + (tt * 16 + r) * 266 + nt * 16 + q * 4) = pk;
        }
    }
    __syncthreads();

    // ---- phase 2: layer 2, wave handles out-col tiles {2w, 2w+1} ----
    floatx4 acc2[2][4];
#pragma unroll
    for (int n2 = 0; n2 < 2; n2++)
#pragma unroll
        for (int mt = 0; mt < 4; mt++) acc2[n2][mt] = (floatx4){0.f, 0.f, 0.f, 0.f};
#pragma unroll
    for (int kc = 0; kc < 8; kc++) {
        short8 a2[4];
#pragma unroll
        for (int mt = 0; mt < 4; mt++)
            a2[mt] = *(const short8*)(h1A + (mt * 16 + r) * 266 + kc * 32 + q * 8);
#pragma unroll
        for (int n2 = 0; n2 < 2; n2++) {
            short8 bw = *(const short8*)(W2s + ((wave * 2 + n2) * 8 + kc) * 512 + lane * 8);
#pragma unroll
            for (int mt = 0; mt < 4; mt++)
                acc2[n2][mt] = __builtin_amdgcn_mfma_f32_16x16x32_bf16(a2[mt], bw, acc2[n2][mt], 0, 0, 0);
        }
    }
    __syncthreads();   // all waves done with xA/h1A -> safe to overlay h2T

    // ---- phase 3: bias+relu, h2T[col][tok] via b128 (4 consecutive tokens) ----
#pragma unroll
    for (int n2 = 0; n2 < 2; n2++) {
        const int nt2 = wave * 2 + n2;
        const float bias = b2[nt2 * 16 + r];
#pragma unroll
        for (int mt = 0; mt < 4; mt++) {
            floatx4 v;
#pragma unroll
            for (int i = 0; i < 4; i++) v[i] = fmaxf(acc2[n2][mt][i] + bias, 0.f);
            *(floatx4*)(h2T + (nt2 * 16 + r) * 68 + mt * 16 + q * 4) = v;
        }
    }
    __syncthreads();

    // ---- counts: run heads (few atomics) ----
    if (tid < 64) {
        int s = sseg[tid];
        if (tid == 0 || sseg[tid - 1] != s) {
            int len = 1;
            for (int u = tid + 1; u < 64 && sseg[u] == s; ++u) ++len;
            atomicAdd(&counts[s], (float)len);
        }
    }

    // ---- phase 4: segment sums. 128 threads, one col each; run boundaries are
    // thread-uniform -> each store/atomic instr covers 64 consecutive floats of
    // one segment row. Interior segments are block-exclusive -> plain store
    // (out pre-zeroed); only first/last segment of the block use atomics. ----
    if (tid < 128) {
        const int col = tid;
        const int sfirst = sseg[0], slast = sseg[63];
        const float* hp = h2T + col * 68;
        int cur = sfirst;
        float sum = 0.f;
#pragma unroll
        for (int g = 0; g < 16; g++) {
            floatx4 v = *(const floatx4*)(hp + g * 4);
#pragma unroll
            for (int e = 0; e < 4; e++) {
                int s = sseg[g * 4 + e];
                if (s != cur) {
                    float* dst = &out[(size_t)cur * D_OUT + col];
                    if (cur == sfirst || cur == slast) atomicAdd(dst, sum);
                    else *dst = sum;
                    sum = 0.f; cur = s;
                }
                sum += v[e];
            }
        }
        float* dst = &out[(size_t)cur * D_OUT + col];
        if (cur == sfirst || cur == slast) atomicAdd(dst, sum);
        else *dst = sum;
    }
}

__global__ void div_kernel(float4* __restrict__ out4, const float* __restrict__ counts) {
    int i = blockIdx.x * 256 + threadIdx.x;   // 262144 float4s, 32 per row
    float inv = 1.f / fmaxf(counts[i >> 5], 1.f);
    float4 v = out4[i];
    v.x *= inv; v.y *= inv; v.z *= inv; v.w *= inv;
    out4[i] = v;
}

extern "C" void kernel_launch(void* const* d_in, const int* in_sizes, int n_in,
                              void* d_out, int out_size, void* d_ws, size_t ws_size,
                              hipStream_t stream) {
    const float* x  = (const float*)d_in[0];
    const int* seg  = (const int*)d_in[1];
    const float* W1 = (const float*)d_in[3];
    const float* b1 = (const float*)d_in[4];
    const float* W2 = (const float*)d_in[5];
    const float* b2 = (const float*)d_in[6];
    float* out = (float*)d_out;

    float* counts       = (float*)d_ws;                                   // 32 KB
    unsigned short* W1s = (unsigned short*)((char*)d_ws + 32768);         // 64 KB
    unsigned short* W2s = (unsigned short*)((char*)d_ws + 32768 + 65536); // 64 KB

    hipLaunchKernelGGL(setup_kernel, dim3(1064), dim3(256), 0, stream,
                       W1, W2, W1s, W2s, (float4*)out, (float4*)counts);
    hipLaunchKernelGGL(ds_main, dim3(4096), dim3(256), 0, stream,
                       x, seg, W1s, b1, W2s, b2, out, counts);
    hipLaunchKernelGGL(div_kernel, dim3(1024), dim3(256), 0, stream,
                       (float4*)out, counts);
}